// Round 6
// baseline (116.196 us; speedup 1.0000x reference)
//
#include <hip/hip_runtime.h>
#include <math.h>

typedef short  bf16x8 __attribute__((ext_vector_type(8)));
typedef float  f32x16 __attribute__((ext_vector_type(16)));

constexpr int BATCH = 4, NPTS = 8192;
constexpr int CLOUD = BATCH * NPTS;     // 32768 points per cloud

__device__ inline unsigned short bf16_rne(float x) {
    unsigned int u = __float_as_uint(x);
    return (unsigned short)((u + 0x7FFFu + ((u >> 16) & 1u)) >> 16);
}
__device__ inline float bf16_val(unsigned short h) {
    return __uint_as_float(((unsigned int)h) << 16);
}

// ---------------- prep: init dist=+inf; build A-role / B-role bf16 packs.
// K=16 slots. A[n]: [hx,lx,hx, hy,ly,hy, hz,lz,hz, 1,1,1, r0,r1,r2, 0]
//             B[m]: [htx,htx,ltx, hty,hty,lty, htz,htz,ltz, s0,s1,s2, 1,1,1, 0]
// (t = -2*coord; r,s = 3-way bf16 splits of |p|^2)  =>  sum_k A*B ~= d^2.
__global__ __launch_bounds__(256) void cd_prep(
    const float* __restrict__ x1, const float* __restrict__ x2,
    uint4* __restrict__ APK, uint4* __restrict__ BPK,
    unsigned int* __restrict__ dist) {
    const int i = blockIdx.x * 256 + threadIdx.x;   // 0 .. 2*CLOUD-1
    dist[i] = 0x7F800000u;                          // +inf
    const float* src = (i < CLOUD) ? x1 : x2;
    const int idx = i & (CLOUD - 1);
    const float x = src[idx*3+0], y = src[idx*3+1], z = src[idx*3+2];
    const float r = x*x + y*y + z*z;

    const unsigned short one = 0x3F80u;
    const unsigned short r0 = bf16_rne(r);
    const float rm1 = r - bf16_val(r0);
    const unsigned short r1 = bf16_rne(rm1);
    const unsigned short r2 = bf16_rne(rm1 - bf16_val(r1));

    const unsigned short hx = bf16_rne(x), hy = bf16_rne(y), hz = bf16_rne(z);
    const unsigned short lx = bf16_rne(x - bf16_val(hx));
    const unsigned short ly = bf16_rne(y - bf16_val(hy));
    const unsigned short lz = bf16_rne(z - bf16_val(hz));
    uint4 a0, a1;
    a0.x = (unsigned)hx | ((unsigned)lx << 16);
    a0.y = (unsigned)hx | ((unsigned)hy << 16);
    a0.z = (unsigned)ly | ((unsigned)hy << 16);
    a0.w = (unsigned)hz | ((unsigned)lz << 16);
    a1.x = (unsigned)hz | ((unsigned)one << 16);
    a1.y = (unsigned)one | ((unsigned)one << 16);
    a1.z = (unsigned)r0 | ((unsigned)r1 << 16);
    a1.w = (unsigned)r2;
    APK[2*i+0] = a0;  APK[2*i+1] = a1;

    const float tx = -2.f*x, ty = -2.f*y, tz = -2.f*z;
    const unsigned short ax = bf16_rne(tx), ay = bf16_rne(ty), az = bf16_rne(tz);
    const unsigned short bx = bf16_rne(tx - bf16_val(ax));
    const unsigned short by = bf16_rne(ty - bf16_val(ay));
    const unsigned short bz = bf16_rne(tz - bf16_val(az));
    uint4 b0, b1;
    b0.x = (unsigned)ax | ((unsigned)ax << 16);
    b0.y = (unsigned)bx | ((unsigned)ay << 16);
    b0.z = (unsigned)ay | ((unsigned)by << 16);
    b0.w = (unsigned)az | ((unsigned)az << 16);
    b1.x = (unsigned)bz | ((unsigned)r0 << 16);
    b1.y = (unsigned)r1 | ((unsigned)r2 << 16);
    b1.z = (unsigned)one | ((unsigned)one << 16);
    b1.w = (unsigned)one;
    BPK[2*i+0] = b0;  BPK[2*i+1] = b1;
}

// ---------------- gemm+min: 1-wave block = 128 rows x 1024-col sweep.
// wid bits: dir(1) | b(2) | cc(3) | rg(6). MFMA 32x32x16, K=16.
__global__ __launch_bounds__(64, 3) void cd_gemm(
    const uint4* __restrict__ APK, const uint4* __restrict__ BPK,
    unsigned int* __restrict__ dist) {

    __shared__ float lbuf[32][33];

    const int l = threadIdx.x;                 // 0..63
    const int lane31 = l & 31, half = l >> 5;

    const int wid = blockIdx.x;                // 0..4095
    const int dir = wid >> 11;
    const int b   = (wid >> 9) & 3;
    const int cc  = (wid >> 6) & 7;
    const int rg  = wid & 63;

    const int aBase = (dir ? CLOUD : 0) + b * NPTS + rg * 128;
    const int bBase = (dir ? 0 : CLOUD) + b * NPTS + cc * 1024;

    // A fragments: lane supplies row = l&31, k-slice = 8*half..+7
    bf16x8 afr[4];
#pragma unroll
    for (int f = 0; f < 4; ++f) {
        uint4 v = APK[(size_t)(aBase + f*32 + lane31) * 2 + half];
        __builtin_memcpy(&afr[f], &v, 16);
    }

    f32x16 zc;
#pragma unroll
    for (int i = 0; i < 16; ++i) zc[i] = 0.0f;

    float racc[4][16];
#pragma unroll
    for (int f = 0; f < 4; ++f)
#pragma unroll
        for (int r = 0; r < 16; ++r) racc[f][r] = INFINITY;

    // B tile-pair sweep: pair p covers cols bBase + p*64 .. +63
    uint4 u0, v0, u1, v1;
    const size_t bofs = (size_t)(bBase + lane31) * 2 + half;
#define CD_LD(U, V, PR) \
    U = BPK[bofs + (PR) * 128]; V = BPK[bofs + (PR) * 128 + 64];
#define CD_COMP(U, V)                                                        \
    {                                                                        \
        bf16x8 ba, bb;                                                       \
        __builtin_memcpy(&ba, &U, 16);                                       \
        __builtin_memcpy(&bb, &V, 16);                                       \
        _Pragma("unroll")                                                    \
        for (int f = 0; f < 4; ++f) {                                        \
            f32x16 cA = __builtin_amdgcn_mfma_f32_32x32x16_bf16(             \
                afr[f], ba, zc, 0, 0, 0);                                    \
            f32x16 cB = __builtin_amdgcn_mfma_f32_32x32x16_bf16(             \
                afr[f], bb, zc, 0, 0, 0);                                    \
            _Pragma("unroll")                                                \
            for (int r = 0; r < 16; ++r)                                     \
                racc[f][r] = fminf(fminf(cA[r], cB[r]), racc[f][r]);         \
        }                                                                    \
    }

    CD_LD(u0, v0, 0);
    for (int p = 0; p < 14; p += 2) {
        CD_LD(u1, v1, p + 1);
        CD_COMP(u0, v0);
        CD_LD(u0, v0, p + 2);
        CD_COMP(u1, v1);
    }
    CD_LD(u1, v1, 15);
    CD_COMP(u0, v0);
    CD_COMP(u1, v1);
#undef CD_LD
#undef CD_COMP

    // epilogue: per frag, LDS transpose (33-stride, conflict-free) + row min
    const int distBase = dir * CLOUD + b * NPTS + rg * 128;
#pragma unroll
    for (int f = 0; f < 4; ++f) {
#pragma unroll
        for (int r = 0; r < 16; ++r) {
            const int rl = (r & 3) + 8 * (r >> 2) + 4 * half;  // C/D row map
            lbuf[rl][lane31] = racc[f][r];
        }
        const int row = l >> 1;
        float m = INFINITY;
#pragma unroll
        for (int i = 0; i < 16; ++i)
            m = fminf(m, lbuf[row][(l & 1) * 16 + i]);
        m = fminf(m, __shfl_xor(m, 1, 64));
        if ((l & 1) == 0)
            atomicMin(&dist[distBase + f * 32 + row],
                      __float_as_uint(fmaxf(m, 0.0f)));
    }
}

// ---------------- final: deterministic sum + means
__global__ __launch_bounds__(1024) void cd_reduce(
    const float* __restrict__ dm /* 2*CLOUD floats */, float* __restrict__ out) {
    __shared__ float sw[16];
    const int t = threadIdx.x;
    const float4* v = reinterpret_cast<const float4*>(dm);
    float s = 0.0f;
#pragma unroll 4
    for (int i = t; i < 2 * CLOUD / 4; i += 1024) {
        float4 x = v[i];
        s += (x.x + x.y) + (x.z + x.w);
    }
#pragma unroll
    for (int off = 32; off > 0; off >>= 1) s += __shfl_down(s, off, 64);
    if ((t & 63) == 0) sw[t >> 6] = s;
    __syncthreads();
    if (t == 0) {
        float tot = 0.0f;
#pragma unroll
        for (int w = 0; w < 16; ++w) tot += sw[w];
        out[0] = tot / (float)CLOUD;
    }
}

extern "C" void kernel_launch(void* const* d_in, const int* in_sizes, int n_in,
                              void* d_out, int out_size, void* d_ws, size_t ws_size,
                              hipStream_t stream) {
    const float* xyz1 = (const float*)d_in[0];
    const float* xyz2 = (const float*)d_in[1];
    unsigned int* dist = (unsigned int*)d_ws;                       // 256 KB
    uint4* APK = (uint4*)((char*)d_ws + 2u * CLOUD * 4u);           // 2 MB
    uint4* BPK = (uint4*)((char*)d_ws + 2u * CLOUD * 4u + 2u * CLOUD * 32u); // 2 MB
    float* out = (float*)d_out;

    cd_prep<<<2 * CLOUD / 256, 256, 0, stream>>>(xyz1, xyz2, APK, BPK, dist);
    cd_gemm<<<4096, 64, 0, stream>>>(APK, BPK, dist);
    cd_reduce<<<1, 1024, 0, stream>>>((const float*)dist, out);
}

// Round 7
// 40.431 us; speedup vs baseline: 2.8739x; 2.8739x over previous
//
#include <hip/hip_runtime.h>
#include <math.h>

typedef short  bf16x8 __attribute__((ext_vector_type(8)));
typedef float  f32x16 __attribute__((ext_vector_type(16)));

constexpr int BATCH = 4, NPTS = 8192;
constexpr int CLOUD = BATCH * NPTS;     // 32768 points per cloud

__device__ inline unsigned short bf16_rne(float x) {
    unsigned int u = __float_as_uint(x);
    return (unsigned short)((u + 0x7FFFu + ((u >> 16) & 1u)) >> 16);
}
__device__ inline float bf16_val(unsigned short h) {
    return __uint_as_float(((unsigned int)h) << 16);
}

// ---------------- prep: init dist=+inf; build A-role / B-role bf16 packs.
// K=16 slots. A[n]: [hx,lx,hx, hy,ly,hy, hz,lz,hz, 1,1,1, r0,r1,r2, 0]
//             B[m]: [htx,htx,ltx, hty,hty,lty, htz,htz,ltz, s0,s1,s2, 1,1,1, 0]
// (t = -2*coord; r,s = 3-way bf16 splits of |p|^2)  =>  sum_k A*B ~= d^2.
__global__ __launch_bounds__(256) void cd_prep(
    const float* __restrict__ x1, const float* __restrict__ x2,
    uint4* __restrict__ APK, uint4* __restrict__ BPK,
    unsigned int* __restrict__ dist) {
    const int i = blockIdx.x * 256 + threadIdx.x;   // 0 .. 2*CLOUD-1
    dist[i] = 0x7F800000u;                          // +inf
    const float* src = (i < CLOUD) ? x1 : x2;
    const int idx = i & (CLOUD - 1);
    const float x = src[idx*3+0], y = src[idx*3+1], z = src[idx*3+2];
    const float r = x*x + y*y + z*z;

    const unsigned short one = 0x3F80u;
    const unsigned short r0 = bf16_rne(r);
    const float rm1 = r - bf16_val(r0);
    const unsigned short r1 = bf16_rne(rm1);
    const unsigned short r2 = bf16_rne(rm1 - bf16_val(r1));

    const unsigned short hx = bf16_rne(x), hy = bf16_rne(y), hz = bf16_rne(z);
    const unsigned short lx = bf16_rne(x - bf16_val(hx));
    const unsigned short ly = bf16_rne(y - bf16_val(hy));
    const unsigned short lz = bf16_rne(z - bf16_val(hz));
    uint4 a0, a1;
    a0.x = (unsigned)hx | ((unsigned)lx << 16);
    a0.y = (unsigned)hx | ((unsigned)hy << 16);
    a0.z = (unsigned)ly | ((unsigned)hy << 16);
    a0.w = (unsigned)hz | ((unsigned)lz << 16);
    a1.x = (unsigned)hz | ((unsigned)one << 16);
    a1.y = (unsigned)one | ((unsigned)one << 16);
    a1.z = (unsigned)r0 | ((unsigned)r1 << 16);
    a1.w = (unsigned)r2;
    APK[2*i+0] = a0;  APK[2*i+1] = a1;

    const float tx = -2.f*x, ty = -2.f*y, tz = -2.f*z;
    const unsigned short ax = bf16_rne(tx), ay = bf16_rne(ty), az = bf16_rne(tz);
    const unsigned short bx = bf16_rne(tx - bf16_val(ax));
    const unsigned short by = bf16_rne(ty - bf16_val(ay));
    const unsigned short bz = bf16_rne(tz - bf16_val(az));
    uint4 b0, b1;
    b0.x = (unsigned)ax | ((unsigned)ax << 16);
    b0.y = (unsigned)bx | ((unsigned)ay << 16);
    b0.z = (unsigned)ay | ((unsigned)by << 16);
    b0.w = (unsigned)az | ((unsigned)az << 16);
    b1.x = (unsigned)bz | ((unsigned)r0 << 16);
    b1.y = (unsigned)r1 | ((unsigned)r2 << 16);
    b1.z = (unsigned)one | ((unsigned)one << 16);
    b1.w = (unsigned)one;
    BPK[2*i+0] = b0;  BPK[2*i+1] = b1;
}

// ---------------- gemm+min: wave = 64 rows x 1024-col sweep, MFMA 32x32x16.
// wid bits: dir(1) | b(2) | cc(3) | rg(7).  ~110 VGPR live -> 4 waves/SIMD.
__global__ __launch_bounds__(256) void cd_gemm(
    const uint4* __restrict__ APK, const uint4* __restrict__ BPK,
    unsigned int* __restrict__ dist) {

    __shared__ float lbuf[4][32][33];

    const int tid = threadIdx.x;
    const int wv  = tid >> 6;
    const int l   = tid & 63;
    const int lane31 = l & 31, half = l >> 5;

    const int wid = blockIdx.x * 4 + wv;       // 0..8191
    const int dir = wid >> 12;
    const int b   = (wid >> 10) & 3;
    const int cc  = (wid >> 7) & 7;
    const int rg  = wid & 127;                 // 128 row-groups of 64 rows

    const int aBase = (dir ? CLOUD : 0) + b * NPTS + rg * 64;
    const int bBase = (dir ? 0 : CLOUD) + b * NPTS + cc * 1024;

    // A fragments (2): lane supplies row = l&31, k-slice = 8*half..+7
    bf16x8 afr0, afr1;
    {
        uint4 v0 = APK[(size_t)(aBase + lane31) * 2 + half];
        uint4 v1 = APK[(size_t)(aBase + 32 + lane31) * 2 + half];
        __builtin_memcpy(&afr0, &v0, 16);
        __builtin_memcpy(&afr1, &v1, 16);
    }

    f32x16 zc;
#pragma unroll
    for (int i = 0; i < 16; ++i) zc[i] = 0.0f;

    float racc[2][16];
#pragma unroll
    for (int f = 0; f < 2; ++f)
#pragma unroll
        for (int r = 0; r < 16; ++r) racc[f][r] = INFINITY;

    // B tile-pair sweep: pair p covers cols bBase + p*64 .. +63
    uint4 u0, v0, u1, v1;
    const size_t bofs = (size_t)(bBase + lane31) * 2 + half;
#define CD_LD(U, V, PR) \
    U = BPK[bofs + (PR) * 128]; V = BPK[bofs + (PR) * 128 + 64];
#define CD_COMP(U, V)                                                        \
    {                                                                        \
        bf16x8 ba, bb;                                                       \
        __builtin_memcpy(&ba, &U, 16);                                       \
        __builtin_memcpy(&bb, &V, 16);                                       \
        f32x16 c0 = __builtin_amdgcn_mfma_f32_32x32x16_bf16(afr0, ba, zc, 0, 0, 0); \
        f32x16 c1 = __builtin_amdgcn_mfma_f32_32x32x16_bf16(afr0, bb, zc, 0, 0, 0); \
        f32x16 c2 = __builtin_amdgcn_mfma_f32_32x32x16_bf16(afr1, ba, zc, 0, 0, 0); \
        f32x16 c3 = __builtin_amdgcn_mfma_f32_32x32x16_bf16(afr1, bb, zc, 0, 0, 0); \
        _Pragma("unroll")                                                    \
        for (int r = 0; r < 16; ++r) {                                       \
            racc[0][r] = fminf(fminf(c0[r], c1[r]), racc[0][r]);             \
            racc[1][r] = fminf(fminf(c2[r], c3[r]), racc[1][r]);             \
        }                                                                    \
    }

    CD_LD(u0, v0, 0);
    for (int p = 0; p < 14; p += 2) {
        CD_LD(u1, v1, p + 1);
        CD_COMP(u0, v0);
        CD_LD(u0, v0, p + 2);
        CD_COMP(u1, v1);
    }
    CD_LD(u1, v1, 15);
    CD_COMP(u0, v0);
    CD_COMP(u1, v1);
#undef CD_LD
#undef CD_COMP

    // epilogue: per frag, LDS transpose (33-stride, conflict-free) + row min
    const int distBase = dir * CLOUD + b * NPTS + rg * 64;
#pragma unroll
    for (int f = 0; f < 2; ++f) {
#pragma unroll
        for (int r = 0; r < 16; ++r) {
            const int rl = (r & 3) + 8 * (r >> 2) + 4 * half;  // C/D row map
            lbuf[wv][rl][lane31] = racc[f][r];
        }
        const int row = l >> 1;
        float m = INFINITY;
#pragma unroll
        for (int i = 0; i < 16; ++i)
            m = fminf(m, lbuf[wv][row][(l & 1) * 16 + i]);
        m = fminf(m, __shfl_xor(m, 1, 64));
        if ((l & 1) == 0)
            atomicMin(&dist[distBase + f * 32 + row],
                      __float_as_uint(fmaxf(m, 0.0f)));
    }
}

// ---------------- final: deterministic sum + means
__global__ __launch_bounds__(1024) void cd_reduce(
    const float* __restrict__ dm /* 2*CLOUD floats */, float* __restrict__ out) {
    __shared__ float sw[16];
    const int t = threadIdx.x;
    const float4* v = reinterpret_cast<const float4*>(dm);
    float s = 0.0f;
#pragma unroll 4
    for (int i = t; i < 2 * CLOUD / 4; i += 1024) {
        float4 x = v[i];
        s += (x.x + x.y) + (x.z + x.w);
    }
#pragma unroll
    for (int off = 32; off > 0; off >>= 1) s += __shfl_down(s, off, 64);
    if ((t & 63) == 0) sw[t >> 6] = s;
    __syncthreads();
    if (t == 0) {
        float tot = 0.0f;
#pragma unroll
        for (int w = 0; w < 16; ++w) tot += sw[w];
        out[0] = tot / (float)CLOUD;
    }
}

extern "C" void kernel_launch(void* const* d_in, const int* in_sizes, int n_in,
                              void* d_out, int out_size, void* d_ws, size_t ws_size,
                              hipStream_t stream) {
    const float* xyz1 = (const float*)d_in[0];
    const float* xyz2 = (const float*)d_in[1];
    unsigned int* dist = (unsigned int*)d_ws;                       // 256 KB
    uint4* APK = (uint4*)((char*)d_ws + 2u * CLOUD * 4u);           // 2 MB
    uint4* BPK = (uint4*)((char*)d_ws + 2u * CLOUD * 4u + 2u * CLOUD * 32u); // 2 MB
    float* out = (float*)d_out;

    cd_prep<<<2 * CLOUD / 256, 256, 0, stream>>>(xyz1, xyz2, APK, BPK, dist);
    cd_gemm<<<2048, 256, 0, stream>>>(APK, BPK, dist);
    cd_reduce<<<1, 1024, 0, stream>>>((const float*)dist, out);
}

// Round 8
// 39.253 us; speedup vs baseline: 2.9602x; 1.0300x over previous
//
#include <hip/hip_runtime.h>
#include <math.h>

typedef short  bf16x8 __attribute__((ext_vector_type(8)));
typedef float  f32x16 __attribute__((ext_vector_type(16)));

constexpr int BATCH = 4, NPTS = 8192;
constexpr int CLOUD = BATCH * NPTS;     // 32768 points per cloud

__device__ inline unsigned short bf16_rne(float x) {
    unsigned int u = __float_as_uint(x);
    return (unsigned short)((u + 0x7FFFu + ((u >> 16) & 1u)) >> 16);
}
__device__ inline float bf16_val(unsigned short h) {
    return __uint_as_float(((unsigned int)h) << 16);
}

// ---------------- prep: init dist=+inf; build A-role / B-role bf16 packs.
// K=16 slots. A[n]: [hx,lx,hx, hy,ly,hy, hz,lz,hz, 1,1,1, r0,r1,r2, 0]
//             B[m]: [htx,htx,ltx, hty,hty,lty, htz,htz,ltz, s0,s1,s2, 1,1,1, 0]
// (t = -2*coord; r,s = 3-way bf16 splits of |p|^2)  =>  sum_k A*B ~= d^2.
// Layout: FRAGMENT-MAJOR interleave, uint4_idx(pt, half) =
//   (pt>>5)*64 + half*32 + (pt&31)
// so a wave's 64 lanes (lane = half*32 + col) read CONSECUTIVE uint4s.
__global__ __launch_bounds__(256) void cd_prep(
    const float* __restrict__ x1, const float* __restrict__ x2,
    uint4* __restrict__ APK, uint4* __restrict__ BPK,
    unsigned int* __restrict__ dist) {
    const int i = blockIdx.x * 256 + threadIdx.x;   // 0 .. 2*CLOUD-1
    dist[i] = 0x7F800000u;                          // +inf
    const float* src = (i < CLOUD) ? x1 : x2;
    const int idx = i & (CLOUD - 1);
    const float x = src[idx*3+0], y = src[idx*3+1], z = src[idx*3+2];
    const float r = x*x + y*y + z*z;

    const unsigned short one = 0x3F80u;
    const unsigned short r0 = bf16_rne(r);
    const float rm1 = r - bf16_val(r0);
    const unsigned short r1 = bf16_rne(rm1);
    const unsigned short r2 = bf16_rne(rm1 - bf16_val(r1));

    const unsigned short hx = bf16_rne(x), hy = bf16_rne(y), hz = bf16_rne(z);
    const unsigned short lx = bf16_rne(x - bf16_val(hx));
    const unsigned short ly = bf16_rne(y - bf16_val(hy));
    const unsigned short lz = bf16_rne(z - bf16_val(hz));
    uint4 a0, a1;
    a0.x = (unsigned)hx | ((unsigned)lx << 16);
    a0.y = (unsigned)hx | ((unsigned)hy << 16);
    a0.z = (unsigned)ly | ((unsigned)hy << 16);
    a0.w = (unsigned)hz | ((unsigned)lz << 16);
    a1.x = (unsigned)hz | ((unsigned)one << 16);
    a1.y = (unsigned)one | ((unsigned)one << 16);
    a1.z = (unsigned)r0 | ((unsigned)r1 << 16);
    a1.w = (unsigned)r2;

    const float tx = -2.f*x, ty = -2.f*y, tz = -2.f*z;
    const unsigned short ax = bf16_rne(tx), ay = bf16_rne(ty), az = bf16_rne(tz);
    const unsigned short bx = bf16_rne(tx - bf16_val(ax));
    const unsigned short by = bf16_rne(ty - bf16_val(ay));
    const unsigned short bz = bf16_rne(tz - bf16_val(az));
    uint4 b0, b1;
    b0.x = (unsigned)ax | ((unsigned)ax << 16);
    b0.y = (unsigned)bx | ((unsigned)ay << 16);
    b0.z = (unsigned)ay | ((unsigned)by << 16);
    b0.w = (unsigned)az | ((unsigned)az << 16);
    b1.x = (unsigned)bz | ((unsigned)r0 << 16);
    b1.y = (unsigned)r1 | ((unsigned)r2 << 16);
    b1.z = (unsigned)one | ((unsigned)one << 16);
    b1.w = (unsigned)one;

    const int g = i >> 5, w = i & 31;
    APK[g*64 + w]      = a0;  APK[g*64 + 32 + w] = a1;
    BPK[g*64 + w]      = b0;  BPK[g*64 + 32 + w] = b1;
}

// ---------------- gemm+min: block = 4 waves x 64 rows, SHARED 1024-col
// B-chunk staged once in LDS (32 KB, linear copy, conflict-free reads).
// wid bits: dir(1) | b(2) | cc(3) | rg(7); block's 4 waves share cc.
__global__ __launch_bounds__(256) void cd_gemm(
    const uint4* __restrict__ APK, const uint4* __restrict__ BPK,
    unsigned int* __restrict__ dist) {

    __shared__ uint4 Blds[2048];          // 32 KB: B chunk, fragment-major
    __shared__ float lbuf[4][32][33];     // epilogue transpose

    const int tid = threadIdx.x;
    const int wv  = tid >> 6;
    const int l   = tid & 63;
    const int lane31 = l & 31, half = l >> 5;

    const int wid = blockIdx.x * 4 + wv;       // 0..8191
    const int dir = wid >> 12;
    const int b   = (wid >> 10) & 3;
    const int cc  = (wid >> 7) & 7;
    const int rg  = wid & 127;                 // 128 row-groups of 64 rows

    const int aPt = (dir ? CLOUD : 0) + b * NPTS + rg * 64;
    const int bPt = (dir ? 0 : CLOUD) + b * NPTS + cc * 1024;

    // ---- stage B chunk: 2048 uint4, linear coalesced copy
    {
        const uint4* src = BPK + (size_t)bPt * 2;
#pragma unroll
        for (int k = 0; k < 8; ++k)
            Blds[tid + k * 256] = src[tid + k * 256];
    }

    // ---- A fragments (2): lane l reads consecutive uint4 (coalesced)
    bf16x8 afr0, afr1;
    {
        uint4 v0 = APK[(size_t)aPt * 2 + l];
        uint4 v1 = APK[(size_t)aPt * 2 + 64 + l];
        __builtin_memcpy(&afr0, &v0, 16);
        __builtin_memcpy(&afr1, &v1, 16);
    }

    f32x16 zc;
#pragma unroll
    for (int i = 0; i < 16; ++i) zc[i] = 0.0f;

    float racc[2][16];
#pragma unroll
    for (int f = 0; f < 2; ++f)
#pragma unroll
        for (int r = 0; r < 16; ++r) racc[f][r] = INFINITY;

    __syncthreads();

    // ---- sweep 16 col-pairs: 2 ds_read_b128 (lane-linear, conflict-free)
    //      + 4 MFMA + 32 v_min3 per step. unroll 4 bounds B-reg pressure.
#pragma unroll 4
    for (int p = 0; p < 16; ++p) {
        bf16x8 ba, bb;
        uint4 ua = Blds[(2*p + 0) * 64 + l];
        uint4 ub = Blds[(2*p + 1) * 64 + l];
        __builtin_memcpy(&ba, &ua, 16);
        __builtin_memcpy(&bb, &ub, 16);
        f32x16 c0 = __builtin_amdgcn_mfma_f32_32x32x16_bf16(afr0, ba, zc, 0, 0, 0);
        f32x16 c1 = __builtin_amdgcn_mfma_f32_32x32x16_bf16(afr0, bb, zc, 0, 0, 0);
        f32x16 c2 = __builtin_amdgcn_mfma_f32_32x32x16_bf16(afr1, ba, zc, 0, 0, 0);
        f32x16 c3 = __builtin_amdgcn_mfma_f32_32x32x16_bf16(afr1, bb, zc, 0, 0, 0);
#pragma unroll
        for (int r = 0; r < 16; ++r) {
            racc[0][r] = fminf(fminf(c0[r], c1[r]), racc[0][r]);   // v_min3
            racc[1][r] = fminf(fminf(c2[r], c3[r]), racc[1][r]);
        }
    }

    // ---- epilogue: per frag, LDS transpose (33-stride) + row min + atomicMin
    const int distBase = dir * CLOUD + b * NPTS + rg * 64;
#pragma unroll
    for (int f = 0; f < 2; ++f) {
#pragma unroll
        for (int r = 0; r < 16; ++r) {
            const int rl = (r & 3) + 8 * (r >> 2) + 4 * half;  // C/D row map
            lbuf[wv][rl][lane31] = racc[f][r];
        }
        const int row = l >> 1;
        float m = INFINITY;
#pragma unroll
        for (int i = 0; i < 16; ++i)
            m = fminf(m, lbuf[wv][row][(l & 1) * 16 + i]);
        m = fminf(m, __shfl_xor(m, 1, 64));
        if ((l & 1) == 0)
            atomicMin(&dist[distBase + f * 32 + row],
                      __float_as_uint(fmaxf(m, 0.0f)));
    }
}

// ---------------- final: deterministic sum + means
__global__ __launch_bounds__(1024) void cd_reduce(
    const float* __restrict__ dm /* 2*CLOUD floats */, float* __restrict__ out) {
    __shared__ float sw[16];
    const int t = threadIdx.x;
    const float4* v = reinterpret_cast<const float4*>(dm);
    float s = 0.0f;
#pragma unroll 4
    for (int i = t; i < 2 * CLOUD / 4; i += 1024) {
        float4 x = v[i];
        s += (x.x + x.y) + (x.z + x.w);
    }
#pragma unroll
    for (int off = 32; off > 0; off >>= 1) s += __shfl_down(s, off, 64);
    if ((t & 63) == 0) sw[t >> 6] = s;
    __syncthreads();
    if (t == 0) {
        float tot = 0.0f;
#pragma unroll
        for (int w = 0; w < 16; ++w) tot += sw[w];
        out[0] = tot / (float)CLOUD;
    }
}

extern "C" void kernel_launch(void* const* d_in, const int* in_sizes, int n_in,
                              void* d_out, int out_size, void* d_ws, size_t ws_size,
                              hipStream_t stream) {
    const float* xyz1 = (const float*)d_in[0];
    const float* xyz2 = (const float*)d_in[1];
    unsigned int* dist = (unsigned int*)d_ws;                       // 256 KB
    uint4* APK = (uint4*)((char*)d_ws + 2u * CLOUD * 4u);           // 2 MB
    uint4* BPK = (uint4*)((char*)d_ws + 2u * CLOUD * 4u + 2u * CLOUD * 32u); // 2 MB
    float* out = (float*)d_out;

    cd_prep<<<2 * CLOUD / 256, 256, 0, stream>>>(xyz1, xyz2, APK, BPK, dist);
    cd_gemm<<<2048, 256, 0, stream>>>(APK, BPK, dist);
    cd_reduce<<<1, 1024, 0, stream>>>((const float*)dist, out);
}